// Round 10
// baseline (39.411 us; speedup 1.0000x reference)
//
#include <hip/hip_runtime.h>
#include <hip/hip_bf16.h>
#include <math.h>

#define NB   32
#define CIN  4
#define COUT 64
#define TT   6
#define VV   512
#define P_OFF (NB*COUT*TT*VV)   // out then p in d_out
#define SPLITS 8
#define CH   (VV/SPLITS)        // 64 softmax rows per block
#define NROW 24                 // c*6+t rows of x per batch
#define E_FLOATS (2*NB*VV)      // e_i + e_j in ws
#define BM_U32 (NB*VV*16)       // bitmask: 16 u32 per row (512 bits)
#define PKW  516                // pk row stride (u32)
#define MPK_BLOCKS 4096         // prep: mask-pack blocks

typedef __attribute__((ext_vector_type(8))) short bf16x8;
typedef __attribute__((ext_vector_type(4))) float f32x4;

__device__ inline unsigned int pack2(float a, float b) {
    __hip_bfloat162 h = __float22bfloat162_rn(make_float2(a, b));
    return *reinterpret_cast<unsigned int*>(&h);
}

// ---------------------------------------------------------------------------
// Kernel 1 (prep): blocks [0,4096): pack A[:,7]!=0 into bitmask (1 bit/j).
//   thread t handles row nr = t>>6, byte lane b = t&63, j = b*8..b*8+7.
// blocks [4096,4160): e_i/e_j (collapsed xc->x1->e chain).
// ---------------------------------------------------------------------------
__global__ __launch_bounds__(256) void prep_kernel(
    const float* __restrict__ x,
    const int*   __restrict__ A,
    const float* __restrict__ conv_w,
    const float* __restrict__ conv_b,
    const float* __restrict__ l2_w,
    const float* __restrict__ l2_b,
    const float* __restrict__ l1_w,
    float* __restrict__ e,
    unsigned char* __restrict__ bm)
{
    __shared__ float W1[CIN], W2[CIN], cst[2];
    int tid = threadIdx.x;
    int b   = blockIdx.x;

    if (b < MPK_BLOCKS) {
        size_t t  = (size_t)b*256 + tid;     // 0 .. 1,048,575
        int nr    = (int)(t >> 6);           // row 0..16383 (n*512+i)
        int byt   = (int)(t & 63);
        int n     = nr >> 9, i = nr & 511;
        const int* src = A + (((size_t)(n*8 + 7)*VV + i)*VV) + byt*8;
        int4 a0 = *(const int4*)src;
        int4 a1 = *(const int4*)(src + 4);
        unsigned int byte =
            (unsigned)(a0.x != 0)       | ((unsigned)(a0.y != 0) << 1) |
            ((unsigned)(a0.z != 0) << 2) | ((unsigned)(a0.w != 0) << 3) |
            ((unsigned)(a1.x != 0) << 4) | ((unsigned)(a1.y != 0) << 5) |
            ((unsigned)(a1.z != 0) << 6) | ((unsigned)(a1.w != 0) << 7);
        bm[(size_t)nr*64 + byt] = (unsigned char)byte;
        return;
    }

    // ---- e part ----
    if (tid < CIN) {
        float w1 = 0.f, w2 = 0.f;
        for (int o = 0; o < COUT; ++o) {
            w1 += l1_w[o]        * conv_w[o*CIN + tid];
            w2 += l1_w[COUT + o] * conv_w[o*CIN + tid];
        }
        W1[tid] = w1; W2[tid] = w2;
    }
    if (tid == CIN) {
        float B1 = 0.f, B2 = 0.f, S1 = 0.f, S2 = 0.f;
        for (int o = 0; o < COUT; ++o) {
            B1 += l1_w[o]        * conv_b[o];
            B2 += l1_w[COUT + o] * conv_b[o];
            S1 += l1_w[o];
            S2 += l1_w[COUT + o];
        }
        float Ls = 0.f;
        for (int t = 0; t < TT; ++t) Ls += l2_w[t];
        cst[0] = Ls*B1 + l2_b[0]*S1;
        cst[1] = Ls*B2 + l2_b[0]*S2;
    }
    __syncthreads();

    int idx = (b - MPK_BLOCKS) * 256 + tid;   // n*V + v
    int n = idx >> 9, v = idx & (VV-1);
    float ei = cst[0], ej = cst[1];
    #pragma unroll
    for (int c = 0; c < CIN; ++c) {
        float wc1 = W1[c], wc2 = W2[c];
        #pragma unroll
        for (int t = 0; t < TT; ++t) {
            float xv = x[((n*CIN + c)*TT + t)*VV + v];
            float lw = l2_w[t];
            ei += lw*wc1*xv;
            ej += lw*wc2*xv;
        }
    }
    e[idx]         = ei;
    e[NB*VV + idx] = ej;
}

// ---------------------------------------------------------------------------
// Kernel 2 (fused, MFMA): per block (s,n): 64 softmax rows -> p (f32 global),
// y_part[r][w] = sum_i x[n,r,i]*p[n,i,w] via mfma_f32_16x16x32_bf16.
// Masks come from the packed bitmask staged in LDS (4 KB); e_i staged too.
// ---------------------------------------------------------------------------
__global__ __launch_bounds__(512, 4) void fused_kernel(
    const float* __restrict__ x,
    const unsigned int* __restrict__ bm32,
    const float* __restrict__ e,
    const float* __restrict__ l1_b,
    float*       __restrict__ p,
    float*       __restrict__ ypart)
{
    __shared__ float xst[CH][33];            // [i][r], r24 = ones, 25..32 = 0
    __shared__ unsigned int pk[16][PKW];     // bf16-pair stage for one K-group
    __shared__ unsigned int mlds[CH][16];    // row bitmasks (4 KB)
    __shared__ float eld[CH];                // e_i for the 64 rows

    int s = blockIdx.x;                  // 8 chunks of 64 rows
    int n = blockIdx.y;
    int tid = threadIdx.x;
    int lane = tid & 63;
    int q = tid >> 6;                    // wave 0..7

    // stage xst[i][r]
    for (int idx = tid; idx < CH*33; idx += 512) {
        int r = idx >> 6;                // 0..32
        int i = idx & 63;
        float v = 0.f;
        if (r < NROW)       v = x[((size_t)n*NROW + r)*VV + s*CH + i];
        else if (r == NROW) v = 1.f;     // ones-row -> colsum
        xst[i][r] = v;
    }
    // stage row bitmasks: 64 rows x 16 u32
    for (int l = tid; l < CH*16; l += 512) {
        int il = l >> 4, d = l & 15;
        mlds[il][d] = bm32[((size_t)n*VV + s*CH + il)*16 + d];
    }
    if (tid < CH) eld[tid] = e[n*VV + s*CH + tid];

    float l1b_val = l1_b[0];
    float4 ej0 = *(const float4*)(e + NB*VV + n*VV + lane*8);
    float4 ej1 = *(const float4*)(e + NB*VV + n*VV + lane*8 + 4);
    float ejv[8] = {ej0.x, ej0.y, ej0.z, ej0.w, ej1.x, ej1.y, ej1.z, ej1.w};

    f32x4 acc[2][4];
    #pragma unroll
    for (int mt = 0; mt < 2; ++mt)
        #pragma unroll
        for (int t = 0; t < 4; ++t) acc[mt][t] = (f32x4){0.f, 0.f, 0.f, 0.f};

    bf16x8 afr[2][2];                    // [Kgroup][mtile]

    __syncthreads();                     // mlds/eld/xst ready

    for (int sub = 0; sub < 4; ++sub) {
        int ilA  = sub*16 + q*2;         // local rows ilA, ilA+1
        int i_gA = s*CH + ilA;

        // masks from LDS (broadcast dword + byte extract)
        unsigned int mbA = (mlds[ilA    ][lane >> 2] >> ((lane & 3)*8)) & 0xffu;
        unsigned int mbB = (mlds[ilA + 1][lane >> 2] >> ((lane & 3)*8)) & 0xffu;
        float biasA = eld[ilA]     + l1b_val;
        float biasB = eld[ilA + 1] + l1b_val;

        // ---- softmax rows A & B (j = lane*8 + m) ----
        float svA[8], svB[8];
        #pragma unroll
        for (int m2 = 0; m2 < 8; ++m2) {
            float tA = biasA + ejv[m2]; tA = (tA >= 0.f) ? tA : 0.2f*tA;
            svA[m2] = ((mbA >> m2) & 1u) ? tA : -INFINITY;
            float tB = biasB + ejv[m2]; tB = (tB >= 0.f) ? tB : 0.2f*tB;
            svB[m2] = ((mbB >> m2) & 1u) ? tB : -INFINITY;
        }
        float mA = svA[0], mB = svB[0];
        #pragma unroll
        for (int m2 = 1; m2 < 8; ++m2) {
            mA = fmaxf(mA, svA[m2]); mB = fmaxf(mB, svB[m2]);
        }
        #pragma unroll
        for (int off = 32; off; off >>= 1) {
            mA = fmaxf(mA, __shfl_xor(mA, off));
            mB = fmaxf(mB, __shfl_xor(mB, off));
        }
        float sumA = 0.f, sumB = 0.f;
        if (mA > -INFINITY) {
            #pragma unroll
            for (int m2 = 0; m2 < 8; ++m2) { svA[m2] = __expf(svA[m2]-mA); sumA += svA[m2]; }
        } else {
            #pragma unroll
            for (int m2 = 0; m2 < 8; ++m2) svA[m2] = 0.f;
        }
        if (mB > -INFINITY) {
            #pragma unroll
            for (int m2 = 0; m2 < 8; ++m2) { svB[m2] = __expf(svB[m2]-mB); sumB += svB[m2]; }
        } else {
            #pragma unroll
            for (int m2 = 0; m2 < 8; ++m2) svB[m2] = 0.f;
        }
        #pragma unroll
        for (int off = 32; off; off >>= 1) {
            sumA += __shfl_xor(sumA, off);
            sumB += __shfl_xor(sumB, off);
        }
        float invA = (sumA > 0.f) ? 1.f/sumA : 0.f;
        float invB = (sumB > 0.f) ? 1.f/sumB : 0.f;
        #pragma unroll
        for (int m2 = 0; m2 < 8; ++m2) { svA[m2] *= invA; svB[m2] *= invB; }

        // global p stores (f32 exact, 16B/lane coalesced)
        float* prA = p + ((size_t)(n*VV + i_gA))*VV + lane*8;
        float4 pA03 = {svA[0],svA[1],svA[2],svA[3]}, pA47 = {svA[4],svA[5],svA[6],svA[7]};
        float4 pB03 = {svB[0],svB[1],svB[2],svB[3]}, pB47 = {svB[4],svB[5],svB[6],svB[7]};
        *(float4*)prA            = pA03;
        *(float4*)(prA + 4)      = pA47;
        *(float4*)(prA + VV)     = pB03;
        *(float4*)(prA + VV + 4) = pB47;

        // pk store: pair-row = (sub&1)*8 + q
        {
            int pr = (sub & 1)*8 + q;
            uint4 u0 = {pack2(svA[0],svB[0]), pack2(svA[1],svB[1]),
                        pack2(svA[2],svB[2]), pack2(svA[3],svB[3])};
            uint4 u1 = {pack2(svA[4],svB[4]), pack2(svA[5],svB[5]),
                        pack2(svA[6],svB[6]), pack2(svA[7],svB[7])};
            *(uint4*)&pk[pr][lane*8]     = u0;
            *(uint4*)&pk[pr][lane*8 + 4] = u1;
        }

        if (sub & 1) {
            __syncthreads();             // K-group pk complete

            if (sub == 1) {
                // build A-frags: k = g*32 + (lane>>4)*8 + j, m = mt*16+(lane&15)
                #pragma unroll
                for (int g = 0; g < 2; ++g)
                    #pragma unroll
                    for (int mt = 0; mt < 2; ++mt) {
                        int r  = mt*16 + (lane & 15);
                        int kb = g*32 + (lane >> 4)*8;
                        union { unsigned int u[4]; bf16x8 v; } ua;
                        #pragma unroll
                        for (int t = 0; t < 4; ++t)
                            ua.u[t] = pack2(xst[kb + 2*t][r], xst[kb + 2*t + 1][r]);
                        afr[g][mt] = ua.v;
                    }
            }

            int g = sub >> 1;            // K-group 0 or 1
            #pragma unroll
            for (int t = 0; t < 4; ++t) {
                int ncol = (q*4 + t)*16 + (lane & 15);
                union { unsigned int u[4]; bf16x8 v; } ub;
                #pragma unroll
                for (int jj = 0; jj < 4; ++jj)
                    ub.u[jj] = pk[(lane >> 4)*4 + jj][ncol];
                acc[0][t] = __builtin_amdgcn_mfma_f32_16x16x32_bf16(afr[g][0], ub.v, acc[0][t], 0, 0, 0);
                acc[1][t] = __builtin_amdgcn_mfma_f32_16x16x32_bf16(afr[g][1], ub.v, acc[1][t], 0, 0, 0);
            }
            if (sub == 1) __syncthreads();   // MFMA g0 done before sub2 overwrites pk
        }
    }

    // ---- write ypart: D row = mt*16 + (lane>>4)*4 + reg, col = ncol ----
    float* yo = ypart + (size_t)(s*NB + n)*25*VV;
    #pragma unroll
    for (int mt = 0; mt < 2; ++mt)
        #pragma unroll
        for (int t = 0; t < 4; ++t) {
            int ncol = (q*4 + t)*16 + (lane & 15);
            #pragma unroll
            for (int reg = 0; reg < 4; ++reg) {
                int row = mt*16 + (lane >> 4)*4 + reg;
                if (row < 25)
                    yo[(size_t)row*VV + ncol] = acc[mt][t][reg];
            }
        }
}

// ---------------------------------------------------------------------------
// Kernel 3: out[n,o,t,w] = sum_c conv_w[o,c]*y[c*6+t,w] + conv_b[o]*y[24,w]
// Stages + split-reduces ypart through LDS exactly once.
// ---------------------------------------------------------------------------
__global__ __launch_bounds__(256) void expand_kernel(
    const float* __restrict__ ypart,
    const float* __restrict__ conv_w,
    const float* __restrict__ conv_b,
    float*       __restrict__ out)
{
    __shared__ float ysm[25][64];
    __shared__ float wsm[COUT*CIN];
    __shared__ float bsm[COUT];

    int wc = blockIdx.x;                 // 8 w-chunks of 64
    int n  = blockIdx.y;
    int tid = threadIdx.x;

    if (tid < COUT*CIN) wsm[tid] = conv_w[tid];
    if (tid < COUT)     bsm[tid] = conv_b[tid];

    // stage + reduce splits: 25*64 = 1600 floats as 400 float4
    for (int l4 = tid; l4 < 400; l4 += 256) {
        int r = l4 >> 4, w4 = l4 & 15;
        float4 a = {0.f, 0.f, 0.f, 0.f};
        #pragma unroll
        for (int s = 0; s < SPLITS; ++s) {
            float4 v = *(const float4*)(ypart +
                ((size_t)(s*NB + n)*25 + r)*VV + wc*64 + w4*4);
            a.x += v.x; a.y += v.y; a.z += v.z; a.w += v.w;
        }
        *(float4*)&ysm[r][w4*4] = a;
    }
    __syncthreads();

    int w  = tid & 63;
    int og = tid >> 6;                   // 4 groups x 16 o

    float y[25];
    #pragma unroll
    for (int r = 0; r < 25; ++r) y[r] = ysm[r][w];

    #pragma unroll
    for (int oo = 0; oo < 16; ++oo) {
        int o = og*16 + oo;
        float wb[CIN];
        #pragma unroll
        for (int c = 0; c < CIN; ++c) wb[c] = wsm[o*CIN + c];
        float bo = bsm[o];
        #pragma unroll
        for (int t = 0; t < TT; ++t) {
            float val = bo * y[24];
            #pragma unroll
            for (int c = 0; c < CIN; ++c) val = fmaf(wb[c], y[c*TT + t], val);
            out[((size_t)(n*COUT + o)*TT + t)*VV + wc*64 + w] = val;
        }
    }
}

// ---------------------------------------------------------------------------
extern "C" void kernel_launch(void* const* d_in, const int* in_sizes, int n_in,
                              void* d_out, int out_size, void* d_ws, size_t ws_size,
                              hipStream_t stream)
{
    const float* x      = (const float*)d_in[0];
    const int*   A      = (const int*)  d_in[1];
    const float* conv_w = (const float*)d_in[2];
    const float* conv_b = (const float*)d_in[3];
    const float* l2_w   = (const float*)d_in[4];
    const float* l2_b   = (const float*)d_in[5];
    const float* l1_w   = (const float*)d_in[6];
    const float* l1_b   = (const float*)d_in[7];

    float* out = (float*)d_out;
    float* pP  = out + P_OFF;              // p region of d_out
    float* e   = (float*)d_ws;             // 128 KB
    unsigned int* bm = (unsigned int*)(e + E_FLOATS);      // 1 MB bitmask
    float* yp  = (float*)(bm + BM_U32);    // SPLITS*NB*25*VV f32 = 13.1 MB

    // prep: mask-pack (4096 blocks) + e (64 blocks)
    prep_kernel<<<MPK_BLOCKS + NB*VV/256, 256, 0, stream>>>(
        x, A, conv_w, conv_b, l2_w, l2_b, l1_w, e, (unsigned char*)bm);

    dim3 gf(SPLITS, NB);                   // 256 blocks x 512 thr
    fused_kernel<<<gf, 512, 0, stream>>>(x, bm, e, l1_b, pP, yp);

    dim3 ge(8, NB);                        // 256 blocks
    expand_kernel<<<ge, 256, 0, stream>>>(yp, conv_w, conv_b, out);
}